// Round 11
// baseline (572.643 us; speedup 1.0000x reference)
//
#include <hip/hip_runtime.h>
#include <cstddef>

// ---------------------------------------------------------------------------
// CNN1D_LSTM1 pipeline, round 11: r10 3-launch structure + WORKSPACE FIX
// (r10 placed brbuf/cnt INSIDE S3bg's tail: branch Phase-A stores clobbered
//  the lstm completion counter -> head never ran -> out stayed 0.
//  S3bg = [7385088, 10670080) floats; smalls now start AT 10670080.)
//   conv1p: [prep inlined] conv 16->32 k30 MFMA + fused maxpool -> S2b bf16
//   branch: [conv2 inlined] conv 32->64 k10 MFMA -> private bf16 S3 slice
//           + adaptive maxpool (in-place bf16 doubling) + conv(64->4,k3,p1)
//           + pre-scaled Xg store
//   lstm:   batch-split MFMA 16x16x32 bf16, 1 wave/SIMD, exp2 activations,
//           fused head via last-block device-scope atomics   (r9, 159us)
// ---------------------------------------------------------------------------

typedef __attribute__((ext_vector_type(8))) short bf16x8;
typedef __attribute__((ext_vector_type(4))) float f32x4;
typedef unsigned int uint32;

#define LOG2E 1.4426950408889634f

__device__ __forceinline__ unsigned short f2bf(float f) {
    unsigned u = __float_as_uint(f);
    u += 0x7fffu + ((u >> 16) & 1u);   // RNE
    return (unsigned short)(u >> 16);
}
__device__ __forceinline__ float bf2f(unsigned short h) {
    return __uint_as_float(((unsigned)h) << 16);
}
__device__ __forceinline__ unsigned short bfmax(unsigned short a, unsigned short b) {
    return (bf2f(a) >= bf2f(b)) ? a : b;   // max of bf16 values is one of them
}
__device__ __forceinline__ float exp2_(float x) {
#if __has_builtin(__builtin_amdgcn_exp2f)
    return __builtin_amdgcn_exp2f(x);
#else
    return __expf(0.6931471805599453f * x);
#endif
}
__device__ __forceinline__ float rcp2(float x) {   // 1/(1+2^x); pre-scaled sigmoid
    return __builtin_amdgcn_rcpf(1.0f + exp2_(x));
}
__device__ __forceinline__ float sigm(float x) {
    return __builtin_amdgcn_rcpf(1.0f + __expf(-x));
}
__device__ __forceinline__ float leaky(float v) { return v >= 0.0f ? v : 0.01f * v; }

// ---------------------------------------------------------------------------
// conv1p (+inline prep): grid (26 ttiles, 64 b), 256 thr.
__global__ __launch_bounds__(256) void conv1p_kernel(const float* __restrict__ X,
        const float* __restrict__ w_dw, const float* __restrict__ b_dw,
        const float* __restrict__ w_pw, const float* __restrict__ b_pw,
        unsigned short* __restrict__ S2b, int* __restrict__ cnt) {
    const int b = blockIdx.y, tx = blockIdx.x, tid = threadIdx.x;
    if (tx == 0 && b == 0 && tid == 0) *cnt = 0;   // reset lstm completion counter
    const int l0 = tx * 160;
    __shared__ __align__(16) unsigned short Wl[480 * 40];  // B-frags, rows padded
    __shared__ __align__(16) unsigned short U[192 * 33];   // Xt[224*24] then Ct[192*33]
    __shared__ float beff[32];
    unsigned short* Xt = U;

    // ---- inline prep: effective weights into Wl (B-fragment layout) ----
    for (int cc = tid; cc < 480; cc += 256) {
        const int kc = cc >> 5, rem = cc & 31, ki = rem >> 4, ch = rem & 15;
        const int kappa = kc * 2 + ki;
        float dwr[16];
#pragma unroll
        for (int j = 0; j < 16; ++j) dwr[j] = w_dw[(ch * 16 + j) * 30 + kappa];
        for (int n = 0; n < 32; ++n) {
            const float4* pw4 = (const float4*)(w_pw + n * 256 + ch * 16);
            float s = 0.f;
#pragma unroll
            for (int j4 = 0; j4 < 4; ++j4) {
                float4 p = pw4[j4];
                s += p.x * dwr[j4 * 4] + p.y * dwr[j4 * 4 + 1]
                   + p.z * dwr[j4 * 4 + 2] + p.w * dwr[j4 * 4 + 3];
            }
            Wl[(kc * 32 + n) * 40 + ki * 16 + ch] = f2bf(s);
        }
    }
    if (tid < 32) {
        float s = b_pw[tid];
        const float4* p4 = (const float4*)(w_pw + tid * 256);
        const float4* d4 = (const float4*)b_dw;
        for (int q = 0; q < 64; ++q) {
            float4 p = p4[q], d = d4[q];
            s += p.x * d.x + p.y * d.y + p.z * d.z + p.w * d.w;
        }
        beff[tid] = s;
    }
    // ---- stage X transposed bf16 (float4 global loads) ----
    for (int i = tid; i < 896; i += 256) {
        int ch = i / 56, p4 = (i - ch * 56) * 4;
        int l = l0 + p4;
        float4 v = {0.f, 0.f, 0.f, 0.f};
        const float* xrow = X + ((size_t)b * 16 + ch) * 4096;
        if (l + 3 < 4096 && p4 + 3 < 221) {
            v = *(const float4*)(xrow + l);
        } else {
            float* vv = (float*)&v;
#pragma unroll
            for (int e = 0; e < 4; ++e) {
                int p = p4 + e, le = l + e;
                vv[e] = (p < 221 && le < 4096) ? xrow[le] : 0.f;
            }
        }
        unsigned short* dst = Xt + p4 * 24 + ch;
        dst[0] = f2bf(v.x); dst[24] = f2bf(v.y); dst[48] = f2bf(v.z); dst[72] = f2bf(v.w);
    }
    __syncthreads();
    const int w = tid >> 6, lane = tid & 63, quad = lane >> 4, l16 = lane & 15;
    const int ki = quad >> 1, ch0 = (quad & 1) * 8;
    f32x4 acc[3][2];
#pragma unroll
    for (int mi = 0; mi < 3; ++mi)
#pragma unroll
        for (int nt = 0; nt < 2; ++nt) acc[mi][nt] = (f32x4){0.f, 0.f, 0.f, 0.f};
#pragma unroll
    for (int kc = 0; kc < 15; ++kc) {
        bf16x8 B0 = *(const bf16x8*)(Wl + (kc * 32 + l16) * 40 + quad * 8);
        bf16x8 B1 = *(const bf16x8*)(Wl + (kc * 32 + 16 + l16) * 40 + quad * 8);
#pragma unroll
        for (int mi = 0; mi < 3; ++mi) {
            int mrow = (w + mi * 4) * 16 + l16 + 2 * kc + ki;
            bf16x8 A = *(const bf16x8*)(Xt + mrow * 24 + ch0);
            acc[mi][0] = __builtin_amdgcn_mfma_f32_16x16x32_bf16(A, B0, acc[mi][0], 0, 0, 0);
            acc[mi][1] = __builtin_amdgcn_mfma_f32_16x16x32_bf16(A, B1, acc[mi][1], 0, 0, 0);
        }
    }
    __syncthreads();                 // all Xt reads done; reuse U as Ct
    unsigned short* Ct = U;          // [192][33]
#pragma unroll
    for (int mi = 0; mi < 3; ++mi) {
        int lrow = (w + mi * 4) * 16 + quad * 4;
#pragma unroll
        for (int nt = 0; nt < 2; ++nt) {
            int o = nt * 16 + l16;
            float be = beff[o];
#pragma unroll
            for (int r = 0; r < 4; ++r)
                Ct[(lrow + r) * 33 + o] = f2bf(leaky(acc[mi][nt][r] + be));
        }
    }
    __syncthreads();
    for (int idx = tid; idx < 1024; idx += 256) {    // 32 t x 32 ch
        int ti = idx >> 5, ch = idx & 31;
        int t = tx * 32 + ti;
        if (t < 811) {
            int pmax = 4067 - 5 * t; if (pmax > 20) pmax = 20;   // ceil_mode clamp
            int pbase = 5 * ti;
            float m = bf2f(Ct[pbase * 33 + ch]);
            for (int p = 1; p < pmax; ++p) m = fmaxf(m, bf2f(Ct[(pbase + p) * 33 + ch]));
            S2b[((size_t)b * 32 + ch) * 812 + t] = f2bf(m);
        }
    }
}

// ---------------------------------------------------------------------------
// branch (+inline conv2): grid (64 b, 2 br), 1024 thr (16 waves).
__global__ __launch_bounds__(1024) void branch_kernel(
        const unsigned short* __restrict__ S2b,
        const float* __restrict__ w_c2, const float* __restrict__ b_c2,
        unsigned short* __restrict__ S3bg,
        const float* __restrict__ w_sc0, const float* __restrict__ b_sc0,
        const float* __restrict__ w_ih0, const float* __restrict__ b_ih0, const float* __restrict__ b_hh0,
        const float* __restrict__ w_sc1, const float* __restrict__ b_sc1,
        const float* __restrict__ w_ih1, const float* __restrict__ b_ih1, const float* __restrict__ b_hh1,
        float* __restrict__ Xg0, float* __restrict__ Xg1) {
    const int b = blockIdx.x, br = blockIdx.y;
    const int T = br ? 100 : 300;
    const float* w_sc = br ? w_sc1 : w_sc0;
    const float* b_sc = br ? b_sc1 : b_sc0;
    const float* w_ih = br ? w_ih1 : w_ih0;
    const float* b_ih = br ? b_ih1 : b_ih0;
    const float* b_hh = br ? b_hh1 : b_hh0;
    float* Xg = br ? Xg1 : Xg0;

    __shared__ union __align__(16) {
        struct { unsigned short At[80 * 40]; unsigned short Wl[10 * 64 * 40]; } c2;
        struct { unsigned short bufsb[16][404]; unsigned short Ps[64][302];
                 float xcs[4][304]; } pl;
    } S;

    const int tid = threadIdx.x, wv = tid >> 6, lane = tid & 63;
    const int quad = lane >> 4, l16 = lane & 15;
    unsigned short* myS3 = S3bg + ((size_t)(br * 64 + b) * 64) * 802;

    // ---------------- Phase A: conv2 (batch b), 13 ltiles ----------------
    for (int pair = tid; pair < 2048; pair += 1024) {   // weight self-pack
        int n = pair >> 5, kp = pair & 31;
        const float* src = w_c2 + n * 320 + kp * 10;
        unsigned short* dstc = S.c2.Wl + n * 40 + kp;
#pragma unroll
        for (int kc = 0; kc < 10; ++kc) dstc[kc * 2560] = f2bf(src[kc]);
    }
    const int mt = wv & 3, nt4 = wv >> 2;
    for (int lx = 0; lx < 13; ++lx) {
        const int l0 = lx * 64;
        __syncthreads();   // Wl ready (first iter) / prev At reads done
        for (int i = tid; i < 2560; i += 1024) {
            int ch = i / 80, p = i - ch * 80;
            int l = l0 + p;
            S.c2.At[p * 40 + ch] = (p < 73 && l < 811)
                ? S2b[((size_t)b * 32 + ch) * 812 + l] : (unsigned short)0;
        }
        __syncthreads();
        const int mA = mt * 16 + l16, ch0 = quad * 8;
        f32x4 acc = {0.f, 0.f, 0.f, 0.f};
#pragma unroll
        for (int kc = 0; kc < 10; ++kc) {
            bf16x8 A = *(const bf16x8*)(S.c2.At + (mA + kc) * 40 + ch0);
            bf16x8 Bf = *(const bf16x8*)(S.c2.Wl + (kc * 64 + nt4 * 16 + l16) * 40 + quad * 8);
            acc = __builtin_amdgcn_mfma_f32_16x16x32_bf16(A, Bf, acc, 0, 0, 0);
        }
        const int o = nt4 * 16 + l16;
        const float bc = b_c2[o];
        const int lbase = l0 + mt * 16 + quad * 4;
#pragma unroll
        for (int r = 0; r < 4; ++r) {
            int l = lbase + r;
            if (l < 802) myS3[(size_t)o * 802 + l] = f2bf(leaky(acc[r] + bc));
        }
    }
    __syncthreads();   // drains vmcnt: S3 slice visible via own L1/L2

    // ---------------- Phase B: pool + xc + Xg ----------------
    for (int ci = 0; ci < 4; ++ci) {
        const int c = wv * 4 + ci;
        const unsigned short* row = myS3 + (size_t)c * 802;
        if (br == 0) {
            // bin=300: s=2, k=204 == max over 102 pair-maxes; in-place doubling
            unsigned short* A = S.pl.bufsb[wv];
            for (int it = 0; it < 7; ++it) {
                int q = lane + it * 64;
                if (q < 401) A[q] = bfmax(row[2 * q], row[2 * q + 1]);
            }
            int len = 401;
#pragma unroll
            for (int sp = 1; sp <= 32; sp <<= 1) {
                int nl = len - sp;
                for (int it = 0; it < 7; ++it) {
                    int q = lane + it * 64;
                    if (q < nl) A[q] = bfmax(A[q], A[q + sp]);
                }
                len = nl;
            }
            for (int it = 0; it < 5; ++it) {           // 102 = [t,t+64)U[t+38,t+102)
                int t = lane + it * 64;
                if (t < 300) S.pl.Ps[c][1 + t] = bfmax(A[t], A[t + 38]);
            }
            if (lane < 2) S.pl.Ps[c][lane * 301] = 0;
        } else {
            // bin=100: s=8, k=10 direct
            for (int it = 0; it < 2; ++it) {
                int t = lane + it * 64;
                if (t < 100) {
                    unsigned short m = row[8 * t];
#pragma unroll
                    for (int p = 1; p < 10; ++p) m = bfmax(m, row[8 * t + p]);
                    S.pl.Ps[c][1 + t] = m;
                }
            }
            if (lane < 2) S.pl.Ps[c][lane * 101] = 0;
        }
    }
    __syncthreads();
    // conv k=3 p=1 + leaky -> xcs LDS
    for (int i = tid; i < 4 * T; i += 1024) {
        int o = i / T, t = i - o * T;
        float sum = b_sc[o];
        const float* wvp = w_sc + o * 192;
        for (int c = 0; c < 64; ++c) {
            float p0 = bf2f(S.pl.Ps[c][t]), p1 = bf2f(S.pl.Ps[c][t + 1]),
                  p2 = bf2f(S.pl.Ps[c][t + 2]);
            sum += wvp[c * 3] * p0 + wvp[c * 3 + 1] * p1 + wvp[c * 3 + 2] * p2;
        }
        S.pl.xcs[o][t] = leaky(sum);
    }
    __syncthreads();
    // Xg phase: n = tid&255 gate column, tq = tid>>8 time-phase; pre-scaled
    {
        const int n = tid & 255, tq = tid >> 8;
        const int g = n >> 6;
        const float sc = (g == 2) ? (-2.0f * LOG2E) : (-LOG2E);
        const float4 w4 = *(const float4*)(w_ih + n * 4);
        const float bias = b_ih[n] + b_hh[n];
        const int bt = b >> 4, q2 = (b >> 2) & 3, r = b & 3;
        const int hidx = n & 63;
        const int wv2 = hidx >> 4, lh = hidx & 15;
        const size_t off0 = (((size_t)bt * 4 + wv2) * 64 + q2 * 16 + lh) * 16 + g * 4 + r;
        for (int t = tq; t < T; t += 4) {
            float v = bias + w4.x * S.pl.xcs[0][t] + w4.y * S.pl.xcs[1][t]
                           + w4.z * S.pl.xcs[2][t] + w4.w * S.pl.xcs[3][t];
            Xg[(size_t)t * 16384 + off0] = sc * v;
        }
    }
}

// ---------------------------------------------------------------------------
// lstm (+fused head): grid (4 bt, 2 br), 256 thr, 1 wave/SIMD.  (r9 version)
#define HPAD 72
__global__ __launch_bounds__(256) void lstm_kernel(
    const float* __restrict__ Xg0, const float* __restrict__ Xg1,
    const float* __restrict__ Whh0, const float* __restrict__ Whh1,
    const float* __restrict__ wl0, const float* __restrict__ bl0,
    const float* __restrict__ wl1, const float* __restrict__ bl1,
    float* __restrict__ brbuf, int* __restrict__ cnt,
    const float* __restrict__ w_rul, const float* __restrict__ b_rul,
    float* __restrict__ out) {
    const int bt = blockIdx.x;
    const int br = blockIdx.y;
    const int T = (br == 0) ? 300 : 100;
    const float* Xg = (br == 0) ? Xg0 : Xg1;
    const float* Whh = (br == 0) ? Whh0 : Whh1;
    const float* wl = (br == 0) ? wl0 : wl1;
    const float* bl = (br == 0) ? bl0 : bl1;
    const float C2L = -2.0f * LOG2E;

    __shared__ __align__(16) unsigned short h_lds[2][16][HPAD];
    __shared__ int lastf;

    const int tid = threadIdx.x;
    const int w = tid >> 6, lane = tid & 63, quad = lane >> 4, l16 = lane & 15;
    const int hidx = w * 16 + l16;

    bf16x8 Bf[4][2];
#pragma unroll
    for (int g = 0; g < 4; ++g) {
        const int n = g * 64 + hidx;
        const float scg = (g == 2) ? (-2.0f * LOG2E) : (-LOG2E);
#pragma unroll
        for (int kc = 0; kc < 2; ++kc) {
            const float* src = Whh + n * 64 + kc * 32 + quad * 8;
            bf16x8 v;
#pragma unroll
            for (int j = 0; j < 8; ++j) v[j] = (short)f2bf(src[j] * scg);
            Bf[g][kc] = v;
        }
    }

    for (int i = tid; i < 16 * HPAD; i += 256) (&h_lds[0][0][0])[i] = 0;

    const float* xp = Xg + ((size_t)bt * 4 + w) * 1024 + lane * 16;

    f32x4 xb0[4], xb1[4];
#pragma unroll
    for (int g = 0; g < 4; ++g) xb0[g] = *(const f32x4*)(xp + g * 4);
#pragma unroll
    for (int g = 0; g < 4; ++g) xb1[g] = *(const f32x4*)(xp + 16384 + g * 4);

    float c[4] = {0.f, 0.f, 0.f, 0.f};

    __syncthreads();

    auto step = [&](int t, f32x4* xb) {
        const unsigned short* hrow = &h_lds[t & 1][l16][0];
        bf16x8 A0 = *(const bf16x8*)(hrow + quad * 8);
        bf16x8 A1 = *(const bf16x8*)(hrow + 32 + quad * 8);
        f32x4 ac[4];
#pragma unroll
        for (int g = 0; g < 4; ++g) {
            ac[g] = __builtin_amdgcn_mfma_f32_16x16x32_bf16(A0, Bf[g][0], xb[g], 0, 0, 0);
            ac[g] = __builtin_amdgcn_mfma_f32_16x16x32_bf16(A1, Bf[g][1], ac[g], 0, 0, 0);
        }
        if (t + 2 < T) {
            const float* np = xp + (size_t)(t + 2) * 16384;
#pragma unroll
            for (int g = 0; g < 4; ++g) xb[g] = *(const f32x4*)(np + g * 4);
        }
        const int nb = (t + 1) & 1;
#pragma unroll
        for (int r = 0; r < 4; ++r) {
            float iv = rcp2(ac[0][r]);                 // sigm(i)
            float fv = rcp2(ac[1][r]);                 // sigm(f)
            float gv = 2.0f * rcp2(ac[2][r]) - 1.0f;   // tanh(g)
            float ov = rcp2(ac[3][r]);                 // sigm(o)
            float cs = fv * c[r] + iv * gv;
            c[r] = cs;
            float th = 2.0f * rcp2(cs * C2L) - 1.0f;   // tanh(c)
            h_lds[nb][quad * 4 + r][hidx] = f2bf(ov * th);
        }
        __syncthreads();
    };

    for (int t = 0; t < T; t += 2) {   // T even
        step(t, xb0);
        step(t + 1, xb1);
    }

    // final linear -> brbuf (device-scope atomic stores)
    if (tid < 16) {
        const unsigned short* hrow = &h_lds[0][tid][0];
        float s = bl[0];
        for (int j = 0; j < 64; ++j) s += bf2f(hrow[j]) * wl[j];
        atomicExch(&brbuf[br * 64 + bt * 16 + tid], s);
    }
    __syncthreads();
    __threadfence();
    if (tid == 0) {
        int old = atomicAdd(cnt, 1);
        lastf = (old == 7);
    }
    __syncthreads();
    if (lastf) {                       // last block computes the head
        __threadfence();
        if (tid < 64) {
            float v0 = atomicAdd(&brbuf[tid], 0.0f);        // atomic load
            float v1 = atomicAdd(&brbuf[64 + tid], 0.0f);
            float v = w_rul[0] * v0 + w_rul[1] * v1 + b_rul[0];
            out[tid] = sigm(v);
        }
    }
}

// ---------------------------------------------------------------------------
extern "C" void kernel_launch(void* const* d_in, const int* in_sizes, int n_in,
                              void* d_out, int out_size, void* d_ws, size_t ws_size,
                              hipStream_t stream) {
    const float* X     = (const float*)d_in[0];
    const float* w_dw  = (const float*)d_in[1];
    const float* b_dw  = (const float*)d_in[2];
    const float* w_pw  = (const float*)d_in[3];
    const float* b_pw  = (const float*)d_in[4];
    const float* w_c2  = (const float*)d_in[5];
    const float* b_c2  = (const float*)d_in[6];
    const float* w_sc0 = (const float*)d_in[7];
    const float* b_sc0 = (const float*)d_in[8];
    const float* w_ih0 = (const float*)d_in[9];
    const float* b_ih0 = (const float*)d_in[10];
    const float* w_hh0 = (const float*)d_in[11];
    const float* b_hh0 = (const float*)d_in[12];
    const float* w_l0  = (const float*)d_in[13];
    const float* b_l0  = (const float*)d_in[14];
    const float* w_sc1 = (const float*)d_in[15];
    const float* b_sc1 = (const float*)d_in[16];
    const float* w_ih1 = (const float*)d_in[17];
    const float* b_ih1 = (const float*)d_in[18];
    const float* w_hh1 = (const float*)d_in[19];
    const float* b_hh1 = (const float*)d_in[20];
    const float* w_l1  = (const float*)d_in[21];
    const float* b_l1  = (const float*)d_in[22];
    const float* w_rul = (const float*)d_in[23];
    const float* b_rul = (const float*)d_in[24];

    float* ws = (float*)d_ws;
    float* Xg0 = ws;                                           // [0, 4915200)
    float* Xg1 = ws + 4915200;                                 // [4915200, 6553600)
    unsigned short* S2b  = (unsigned short*)(ws + 6553600);    // 1,662,976 sh -> [6553600, 7385088)
    unsigned short* S3bg = (unsigned short*)(ws + 7385088);    // 6,569,984 sh -> [7385088, 10670080)
    float* brbuf = ws + 10670080;                              // 128 -> [10670080, 10670208)
    int*   cnt   = (int*)(ws + 10670208);                      // 1   (~42.7 MB total)

    conv1p_kernel<<<dim3(26, 64), 256, 0, stream>>>(X, w_dw, b_dw, w_pw, b_pw, S2b, cnt);
    branch_kernel<<<dim3(64, 2), 1024, 0, stream>>>(
        S2b, w_c2, b_c2, S3bg,
        w_sc0, b_sc0, w_ih0, b_ih0, b_hh0,
        w_sc1, b_sc1, w_ih1, b_ih1, b_hh1, Xg0, Xg1);
    lstm_kernel<<<dim3(4, 2), 256, 0, stream>>>(Xg0, Xg1, w_hh0, w_hh1,
                                                w_l0, b_l0, w_l1, b_l1,
                                                brbuf, cnt, w_rul, b_rul, (float*)d_out);
}